// Round 3
// baseline (3393.399 us; speedup 1.0000x reference)
//
#include <hip/hip_runtime.h>

#define BB 256
#define TT 2048
#define HD 100
#define NGP 448   // padded gates per layer: 4 blocks of 112 (16-aligned)

typedef _Float16 h2v __attribute__((ext_vector_type(2)));

__device__ __forceinline__ float fdot2s(unsigned w, unsigned h, float c) {
#if __has_builtin(__builtin_amdgcn_fdot2)
    return __builtin_amdgcn_fdot2(__builtin_bit_cast(h2v, w),
                                  __builtin_bit_cast(h2v, h), c, false);
#else
    h2v av = __builtin_bit_cast(h2v, w), bv = __builtin_bit_cast(h2v, h);
    c = fmaf((float)av[0], (float)bv[0], c);
    c = fmaf((float)av[1], (float)bv[1], c);
    return c;
#endif
}
__device__ __forceinline__ unsigned packh2(float a, float b) {
    h2v p; p[0] = (_Float16)a; p[1] = (_Float16)b;
    return __builtin_bit_cast(unsigned, p);
}
__device__ __forceinline__ float sigmoid_f(float x) {
    return 1.0f / (1.0f + __expf(-x));
}
__device__ __forceinline__ float tanh_f(float x) {
    return 1.0f - 2.0f / (__expf(2.0f * x) + 1.0f);
}

// One block per batch row. 960 threads = 15 waves.
//   tid   0..447 : layer-1 gate threads, padded gate index g=tid
//   tid 448..895 : layer-2 gate threads, padded gate index g=tid-448
//   tid 896..927 : x prefetch wave (32 loaders)
//   tid   0..49  : L1 c/h update (2 units each);  tid 448..497 : L2 update
// Padded gate p: blk=p/112, r=p%112, real source row = blk*100+r iff r<100.
// Pipeline skew: iteration i computes L1 step i and L2 step i-1.
__global__ __launch_bounds__(960, 1) void lstm_fused(
    const float* __restrict__ x,
    const float* __restrict__ w_ih1, const float* __restrict__ w_hh1,
    const float* __restrict__ b_ih1, const float* __restrict__ b_hh1,
    const float* __restrict__ w_ih2, const float* __restrict__ w_hh2,
    const float* __restrict__ b_ih2, const float* __restrict__ b_hh2,
    const float* __restrict__ fc1_w, const float* __restrict__ fc1_b,
    const float* __restrict__ fc2_w, const float* __restrict__ fc2_b,
    float* __restrict__ out)
{
    const int b    = blockIdx.x;
    const int tid  = threadIdx.x;
    const int lane = tid & 63;

    __shared__ unsigned h1p[64];                    // h1 packed f16x2 (50 used)
    __shared__ unsigned h2p[64];                    // h2 packed f16x2
    __shared__ __align__(16) unsigned xb[2][32][4]; // x packed f16x2, dbuf
    __shared__ float g1[NGP];
    __shared__ float g2[NGP];
    __shared__ float h2f[HD];
    __shared__ float fca[25];

    const bool isL1 = (tid < NGP);
    const bool isL2 = (tid >= NGP && tid < 2 * NGP);
    const bool isLd = (tid >= 896 && tid < 928);
    const bool isU1 = (tid < 50);
    const int  u2m  = tid - NGP;
    const bool isU2 = (u2m >= 0 && u2m < 50);

    const int g    = isL2 ? (tid - NGP) : tid;      // padded gate index
    const int blk  = g / 112;
    const int r    = g - blk * 112;
    const int srow = blk * HD + r;                   // real weight row
    const bool real = (isL1 || isL2) && (r < HD);

    unsigned wx[4];
    unsigned wa[50], wb[50];
    float bias = 0.0f;
    float c0 = 0.0f, c1 = 0.0f;                      // update-thread cell state

    wx[0] = wx[1] = wx[2] = wx[3] = 0u;
    #pragma unroll
    for (int q = 0; q < 50; ++q) { wa[q] = 0u; wb[q] = 0u; }

    if (isL1 && real) {
        const float4* ip = (const float4*)(w_ih1 + (size_t)srow * 8);
        float4 v0 = ip[0], v1 = ip[1];
        wx[0] = packh2(v0.x, v0.y); wx[1] = packh2(v0.z, v0.w);
        wx[2] = packh2(v1.x, v1.y); wx[3] = packh2(v1.z, v1.w);
        const float4* hp = (const float4*)(w_hh1 + (size_t)srow * HD);
        #pragma unroll
        for (int q = 0; q < 25; ++q) {
            float4 v = hp[q];
            wa[2*q]   = packh2(v.x, v.y);
            wa[2*q+1] = packh2(v.z, v.w);
        }
        bias = b_ih1[srow] + b_hh1[srow];
    }
    if (isL2 && real) {
        const float4* ip = (const float4*)(w_ih2 + (size_t)srow * HD);
        #pragma unroll
        for (int q = 0; q < 25; ++q) {
            float4 v = ip[q];
            wa[2*q]   = packh2(v.x, v.y);
            wa[2*q+1] = packh2(v.z, v.w);
        }
        const float4* hp = (const float4*)(w_hh2 + (size_t)srow * HD);
        #pragma unroll
        for (int q = 0; q < 25; ++q) {
            float4 v = hp[q];
            wb[2*q]   = packh2(v.x, v.y);
            wb[2*q+1] = packh2(v.z, v.w);
        }
        bias = b_ih2[srow] + b_hh2[srow];
    }

    if (tid < 64) { h1p[tid] = 0u; h2p[tid] = 0u; }
    if (isLd) {   // stage x steps 0..31 into buf 0
        const int s = tid - 896;
        const float4* xp = (const float4*)(x + ((size_t)b * TT + s) * 8);
        float4 a0v = xp[0], a1v = xp[1];
        xb[0][s][0] = packh2(a0v.x, a0v.y); xb[0][s][1] = packh2(a0v.z, a0v.w);
        xb[0][s][2] = packh2(a1v.x, a1v.y); xb[0][s][3] = packh2(a1v.z, a1v.w);
    }
    __syncthreads();

    float4 pa = {0,0,0,0}, pb = {0,0,0,0};

    #pragma unroll 1
    for (int i = 0; i <= TT; ++i) {
        const bool pf = ((i & 31) == 0) && (i + 32 < TT);
        // ---------------- phase 1: gates ----------------
        if (isL1 && i < TT) {
            unsigned st = h1p[lane];                 // pair `lane` of h1(i-1)
            const uint4 xq = *((const uint4*)xb[(i >> 5) & 1][i & 31]); // broadcast
            float a0 = bias, a1 = 0.0f;
            a0 = fdot2s(wx[0], xq.x, a0);
            a1 = fdot2s(wx[1], xq.y, a1);
            a0 = fdot2s(wx[2], xq.z, a0);
            a1 = fdot2s(wx[3], xq.w, a1);
            #pragma unroll
            for (int k = 0; k < 50; ++k) {
                unsigned hk = (unsigned)__builtin_amdgcn_readlane((int)st, k);
                if (k & 1) a1 = fdot2s(wa[k], hk, a1);
                else       a0 = fdot2s(wa[k], hk, a0);
            }
            float acc = a0 + a1;
            g1[g] = (blk == 2) ? tanh_f(acc) : sigmoid_f(acc);
        }
        if (isLd && pf) {   // issue next-chunk x loads
            const float4* xp = (const float4*)(x + ((size_t)b * TT + (i + 32) + (tid - 896)) * 8);
            pa = xp[0]; pb = xp[1];
        }
        if (isL2 && i >= 1) {
            unsigned st1 = h1p[lane];                // h1(i-1)
            unsigned st2 = h2p[lane];                // h2(i-2)
            float a0 = bias, a1 = 0.0f;
            #pragma unroll
            for (int k = 0; k < 50; ++k) {
                unsigned hk = (unsigned)__builtin_amdgcn_readlane((int)st1, k);
                if (k & 1) a1 = fdot2s(wa[k], hk, a1);
                else       a0 = fdot2s(wa[k], hk, a0);
            }
            #pragma unroll
            for (int k = 0; k < 50; ++k) {
                unsigned hk = (unsigned)__builtin_amdgcn_readlane((int)st2, k);
                if (k & 1) a1 = fdot2s(wb[k], hk, a1);
                else       a0 = fdot2s(wb[k], hk, a0);
            }
            float acc = a0 + a1;
            g2[g] = (blk == 2) ? tanh_f(acc) : sigmoid_f(acc);
        }
        __syncthreads();
        // ---------------- phase 2: state update + x LDS write ----------------
        if (isU1 && i < TT) {
            const int m = tid;
            float2 iv = *(const float2*)(g1 + 2*m);
            float2 fv = *(const float2*)(g1 + 112 + 2*m);
            float2 gv = *(const float2*)(g1 + 224 + 2*m);
            float2 ov = *(const float2*)(g1 + 336 + 2*m);
            c0 = fv.x * c0 + iv.x * gv.x;
            c1 = fv.y * c1 + iv.y * gv.y;
            float h0 = ov.x * tanh_f(c0);
            float h1 = ov.y * tanh_f(c1);
            h1p[m] = packh2(h0, h1);
        }
        if (isU2 && i >= 1) {
            const int m = u2m;
            float2 iv = *(const float2*)(g2 + 2*m);
            float2 fv = *(const float2*)(g2 + 112 + 2*m);
            float2 gv = *(const float2*)(g2 + 224 + 2*m);
            float2 ov = *(const float2*)(g2 + 336 + 2*m);
            c0 = fv.x * c0 + iv.x * gv.x;
            c1 = fv.y * c1 + iv.y * gv.y;
            float h0 = ov.x * tanh_f(c0);
            float h1 = ov.y * tanh_f(c1);
            h2p[m] = packh2(h0, h1);
            if (i == TT) { h2f[2*m] = h0; h2f[2*m+1] = h1; }
        }
        if (isLd && pf) {
            const int s  = tid - 896;
            const int nb = ((i >> 5) + 1) & 1;
            xb[nb][s][0] = packh2(pa.x, pa.y); xb[nb][s][1] = packh2(pa.z, pa.w);
            xb[nb][s][2] = packh2(pb.x, pb.y); xb[nb][s][3] = packh2(pb.z, pb.w);
        }
        __syncthreads();
    }

    // ---------------- FC head ----------------
    if (tid < 25) {
        float a = fc1_b[tid];
        const float* wp = fc1_w + tid * HD;
        #pragma unroll
        for (int k = 0; k < HD; ++k) a += h2f[k] * wp[k];
        fca[tid] = a;
    }
    __syncthreads();
    if (tid == 0) {
        float y = fc2_b[0];
        #pragma unroll
        for (int m = 0; m < 25; ++m) y += fca[m] * fc2_w[m];
        out[b] = y;
    }
}

extern "C" void kernel_launch(void* const* d_in, const int* in_sizes, int n_in,
                              void* d_out, int out_size, void* d_ws, size_t ws_size,
                              hipStream_t stream) {
    const float* x     = (const float*)d_in[0];
    const float* w_ih1 = (const float*)d_in[1];
    const float* w_hh1 = (const float*)d_in[2];
    const float* b_ih1 = (const float*)d_in[3];
    const float* b_hh1 = (const float*)d_in[4];
    const float* w_ih2 = (const float*)d_in[5];
    const float* w_hh2 = (const float*)d_in[6];
    const float* b_ih2 = (const float*)d_in[7];
    const float* b_hh2 = (const float*)d_in[8];
    const float* fc1_w = (const float*)d_in[9];
    const float* fc1_b = (const float*)d_in[10];
    const float* fc2_w = (const float*)d_in[11];
    const float* fc2_b = (const float*)d_in[12];
    float* out = (float*)d_out;

    lstm_fused<<<BB, 960, 0, stream>>>(x, w_ih1, w_hh1, b_ih1, b_hh1,
                                       w_ih2, w_hh2, b_ih2, b_hh2,
                                       fc1_w, fc1_b, fc2_w, fc2_b, out);
}